// Round 4
// baseline (2255.722 us; speedup 1.0000x reference)
//
#include <hip/hip_runtime.h>
#include <math.h>

// ---------------------------------------------------------------------------
// AGNN stack: h=relu(x@W1+b1); 32x AGNNConv(beta=1); log_softmax(h@W2+b2)
// N=100000, F=512, H=32, C=40, E=3200000 (+N self loops)
// R8 (resubmit after infra failure): k_agnn is latency-bound (VALU ~15%,
//     req-rate ~12%), and R7 proved the inv-gather was not the limiter.
//     Revert to inv[] arrays (R6 math) and fix the real problem: the rA=rB
//     rotation serialized the gather pipeline to depth ~1. New structure:
//     4 named row buffers, no rotation copies, col indices loaded directly
//     per-quad (no ds_bpermute on the address path), cols prefetched one
//     full group (~4 process slots) ahead of their row gathers. Common case
//     nchunk<=4: all gathers issue back-to-back in the prologue.
// ---------------------------------------------------------------------------

#define HDIM 32
#define NBMAX 1024   // bucket table size (needs N <= 128*1024)
#define BSH 7        // 128 dsts per bucket
#define CHUNK 32768  // edges per partition block
#define TXP 36       // padded x-tile row stride (floats)
#define TWP 36       // padded W-tile row stride (floats)

typedef _Float16 f16;
typedef _Float16 v2h __attribute__((ext_vector_type(2)));

struct __attribute__((aligned(16))) H8 { v2h p[4]; };  // one fp16 half-row (8 elems)
struct __attribute__((aligned(8)))  H4 { v2h p[2]; };  // 4 fp16 elems

#if defined(__has_builtin)
#if __has_builtin(__builtin_amdgcn_fdot2)
#define FDOT2(a, b, c) __builtin_amdgcn_fdot2((a), (b), (c), false)
#endif
#if __has_builtin(__builtin_amdgcn_update_dpp)
#define HAS_DPP 1
#endif
#endif
#ifndef FDOT2
#define FDOT2(a, b, c) fmaf((float)(a)[1], (float)(b)[1], fmaf((float)(a)[0], (float)(b)[0], (c)))
#endif

// sum over each aligned 4-lane quad (lanes l^1, l^2) — DPP, no LDS pipe
static __device__ __forceinline__ float quad_sum(float x) {
#ifdef HAS_DPP
    x += __int_as_float(__builtin_amdgcn_update_dpp(
        0, __float_as_int(x), 0xB1 /*quad_perm [1,0,3,2]*/, 0xF, 0xF, true));
    x += __int_as_float(__builtin_amdgcn_update_dpp(
        0, __float_as_int(x), 0x4E /*quad_perm [2,3,0,1]*/, 0xF, 0xF, true));
#else
    x += __shfl_xor(x, 1);
    x += __shfl_xor(x, 2);
#endif
    return x;
}

static __device__ __forceinline__ int eread(const int* __restrict__ e, int i64, long long idx) {
    return i64 ? e[2 * idx] : e[idx];
}

__global__ void k_flag(const int* __restrict__ e, int* __restrict__ flag) {
    if (blockIdx.x == 0 && threadIdx.x == 0) {
        int z = 0;
        for (int k = 0; k < 64; ++k) z |= e[2 * k + 1];
        *flag = (z == 0) ? 1 : 0;
    }
}

__global__ void k_zero(int* __restrict__ p, int n) {
    int i = blockIdx.x * blockDim.x + threadIdx.x;
    if (i < n) p[i] = 0;
}

// Pass 1: per-block LDS histogram over dst buckets + global reserve.
__launch_bounds__(256) __global__
void k_hist(const int* __restrict__ e, const int* __restrict__ flag,
            int* __restrict__ gc, int* __restrict__ blockOffs,
            long long E, long long M) {
    __shared__ int bh[NBMAX];
    for (int t = threadIdx.x; t < NBMAX; t += 256) bh[t] = 0;
    __syncthreads();
    int i64 = *flag;
    long long base = (long long)blockIdx.x * CHUNK;
    long long end = base + CHUNK < M ? base + CHUNK : M;
    for (long long m = base + threadIdx.x; m < end; m += 256) {
        int d = (m < E) ? eread(e, i64, E + m) : (int)(m - E);
        atomicAdd(&bh[d >> BSH], 1);
    }
    __syncthreads();
    for (int t = threadIdx.x; t < NBMAX; t += 256) {
        int c = bh[t];
        int off = 0;
        if (c) off = atomicAdd(&gc[t], c);
        blockOffs[(size_t)blockIdx.x * NBMAX + t] = off;
    }
}

__launch_bounds__(256) __global__
void k_bscan(const int* __restrict__ gc, int* __restrict__ bbase,
             int* __restrict__ rp, int N) {
    __shared__ int lds[256];
    int t = threadIdx.x;
    int v[4];
#pragma unroll
    for (int d = 0; d < 4; ++d) v[d] = gc[t * 4 + d];
    int tsum = v[0] + v[1] + v[2] + v[3];
    lds[t] = tsum;
    __syncthreads();
    int acc = tsum;
    for (int sh = 1; sh < 256; sh <<= 1) {
        int x = (t >= sh) ? lds[t - sh] : 0;
        __syncthreads();
        acc += x;
        lds[t] = acc;
        __syncthreads();
    }
    if (t == 255) { rp[N] = acc; bbase[NBMAX] = acc; }
    int run = acc - tsum;
#pragma unroll
    for (int d = 0; d < 4; ++d) { bbase[t * 4 + d] = run; run += v[d]; }
}

// Pass 2: partition edges into bucket regions.
__launch_bounds__(256) __global__
void k_part(const int* __restrict__ e, const int* __restrict__ flag,
            const int* __restrict__ bbase, const int* __restrict__ blockOffs,
            int2* __restrict__ pair, long long E, long long M) {
    __shared__ int cur[NBMAX];
    for (int t = threadIdx.x; t < NBMAX; t += 256)
        cur[t] = bbase[t] + blockOffs[(size_t)blockIdx.x * NBMAX + t];
    __syncthreads();
    int i64 = *flag;
    long long base = (long long)blockIdx.x * CHUNK;
    long long end = base + CHUNK < M ? base + CHUNK : M;
    for (long long m = base + threadIdx.x; m < end; m += 256) {
        int s, d;
        if (m < E) { s = eread(e, i64, m); d = eread(e, i64, E + m); }
        else { s = d = (int)(m - E); }
        int pos = atomicAdd(&cur[d >> BSH], 1);
        pair[pos] = make_int2(s, d);
    }
}

// Pass 3: one block per bucket -> fine CSR (rp + col), all LDS atomics.
__launch_bounds__(256) __global__
void k_fine(const int2* __restrict__ pair, const int* __restrict__ bbase,
            int* __restrict__ rp, int* __restrict__ col, int N) {
    __shared__ int cnt[128];
    __shared__ int sc[128];
    int b = blockIdx.x;
    int beg = bbase[b];
    int end = bbase[b + 1];
    int t = threadIdx.x;
    if (t < 128) cnt[t] = 0;
    __syncthreads();
    for (int k = beg + t; k < end; k += 256)
        atomicAdd(&cnt[pair[k].y & 127], 1);
    __syncthreads();
    if (t < 128) sc[t] = cnt[t];
    __syncthreads();
    for (int sh = 1; sh < 128; sh <<= 1) {
        int x = 0;
        if (t < 128 && t >= sh) x = sc[t - sh];
        __syncthreads();
        if (t < 128) sc[t] += x;
        __syncthreads();
    }
    if (t < 128) {
        int basepos = beg + sc[t] - cnt[t];
        int d = (b << BSH) + t;
        if (d < N) rp[d] = basepos;
        cnt[t] = basepos;
    }
    __syncthreads();
    for (int k = beg + t; k < end; k += 256) {
        int2 p = pair[k];
        int pos = atomicAdd(&cnt[p.y & 127], 1);
        col[pos] = p.x;
    }
}

// h = relu(x @ W1 + b1) + fused inv_norm, fp16 h output.
// 128-row tile, thread (cg=tid&7, ty=tid>>3) owns rows {ty+32m} x cols
// {4cg..4cg+3}. 16 k-chunks of 32; x-tile AND W1-chunk double-buffered in
// LDS (strides padded to 36 floats), global loads issued before the
// overlapped compute.
__launch_bounds__(256, 4) __global__
void k_gemm1(const float* __restrict__ x, const float* __restrict__ W1,
             const float* __restrict__ b1, f16* __restrict__ h,
             float* __restrict__ invn, int N) {
    __shared__ float xt[2][128 * TXP];  // 2 x 18432 B
    __shared__ float wt[2][32 * TWP];   // 2 x  4608 B
    int tid = threadIdx.x;
    int cg = tid & 7;   // cols 4cg..4cg+3
    int ty = tid >> 3;  // 0..31
    int rbase = blockIdx.x * 128;
    float4 bias = *(const float4*)(b1 + 4 * cg);
    float acc[4][4];
#pragma unroll
    for (int m = 0; m < 4; ++m) {
        acc[m][0] = bias.x; acc[m][1] = bias.y;
        acc[m][2] = bias.z; acc[m][3] = bias.w;
    }
    float4 gx[4];
    float4 gw;
    // ---- prologue: load + write chunk 0
    {
        int kc = 0;
#pragma unroll
        for (int j = 0; j < 4; ++j) {
            int slot = tid + j * 256;
            int row = slot >> 3, kin = slot & 7;
            int r = rbase + row;
            gx[j] = (r < N) ? *(const float4*)(x + (size_t)r * 512 + kc * 32 + kin * 4)
                            : make_float4(0.f, 0.f, 0.f, 0.f);
        }
        int wrow = tid >> 3, wkin = tid & 7;  // 32 rows x 8 float4
        gw = *(const float4*)(W1 + (size_t)(kc * 32 + wrow) * 32 + wkin * 4);
#pragma unroll
        for (int j = 0; j < 4; ++j) {
            int slot = tid + j * 256;
            int row = slot >> 3, kin = slot & 7;
            *(float4*)(&xt[0][row * TXP + kin * 4]) = gx[j];
        }
        *(float4*)(&wt[0][wrow * TWP + wkin * 4]) = gw;
    }
    __syncthreads();
    for (int kc = 0; kc < 16; ++kc) {
        int buf = kc & 1;
        if (kc + 1 < 16) {  // issue next chunk's global loads early
            int kn = kc + 1;
#pragma unroll
            for (int j = 0; j < 4; ++j) {
                int slot = tid + j * 256;
                int row = slot >> 3, kin = slot & 7;
                int r = rbase + row;
                gx[j] = (r < N) ? *(const float4*)(x + (size_t)r * 512 + kn * 32 + kin * 4)
                                : make_float4(0.f, 0.f, 0.f, 0.f);
            }
            gw = *(const float4*)(W1 + (size_t)(kn * 32 + (tid >> 3)) * 32 + (tid & 7) * 4);
        }
        const float* xb = xt[buf];
        const float* wb = wt[buf];
#pragma unroll
        for (int k4 = 0; k4 < 8; ++k4) {
            float4 w0 = *(const float4*)(wb + (k4 * 4 + 0) * TWP + 4 * cg);
            float4 w1 = *(const float4*)(wb + (k4 * 4 + 1) * TWP + 4 * cg);
            float4 w2 = *(const float4*)(wb + (k4 * 4 + 2) * TWP + 4 * cg);
            float4 w3 = *(const float4*)(wb + (k4 * 4 + 3) * TWP + 4 * cg);
#pragma unroll
            for (int m = 0; m < 4; ++m) {
                float4 xv = *(const float4*)(xb + (ty + 32 * m) * TXP + k4 * 4);
                acc[m][0] = fmaf(xv.x, w0.x, acc[m][0]);
                acc[m][1] = fmaf(xv.x, w0.y, acc[m][1]);
                acc[m][2] = fmaf(xv.x, w0.z, acc[m][2]);
                acc[m][3] = fmaf(xv.x, w0.w, acc[m][3]);
                acc[m][0] = fmaf(xv.y, w1.x, acc[m][0]);
                acc[m][1] = fmaf(xv.y, w1.y, acc[m][1]);
                acc[m][2] = fmaf(xv.y, w1.z, acc[m][2]);
                acc[m][3] = fmaf(xv.y, w1.w, acc[m][3]);
                acc[m][0] = fmaf(xv.z, w2.x, acc[m][0]);
                acc[m][1] = fmaf(xv.z, w2.y, acc[m][1]);
                acc[m][2] = fmaf(xv.z, w2.z, acc[m][2]);
                acc[m][3] = fmaf(xv.z, w2.w, acc[m][3]);
                acc[m][0] = fmaf(xv.w, w3.x, acc[m][0]);
                acc[m][1] = fmaf(xv.w, w3.y, acc[m][1]);
                acc[m][2] = fmaf(xv.w, w3.z, acc[m][2]);
                acc[m][3] = fmaf(xv.w, w3.w, acc[m][3]);
            }
        }
        if (kc + 1 < 16) {  // write next chunk into the other buffer
            int nbuf = buf ^ 1;
#pragma unroll
            for (int j = 0; j < 4; ++j) {
                int slot = tid + j * 256;
                int row = slot >> 3, kin = slot & 7;
                *(float4*)(&xt[nbuf][row * TXP + kin * 4]) = gx[j];
            }
            *(float4*)(&wt[nbuf][(tid >> 3) * TWP + (tid & 7) * 4]) = gw;
            __syncthreads();
        }
    }
#pragma unroll
    for (int m = 0; m < 4; ++m) {
        int r = rbase + ty + 32 * m;
        float hv[4];
        float ss = 0.0f;
#pragma unroll
        for (int j = 0; j < 4; ++j) {
            hv[j] = fmaxf(acc[m][j], 0.0f);
            ss = fmaf(hv[j], hv[j], ss);
        }
        ss += __shfl_xor(ss, 1);
        ss += __shfl_xor(ss, 2);
        ss += __shfl_xor(ss, 4);  // sum over the 8 cg groups
        if (r < N) {
            H4 o;
            o.p[0][0] = (f16)hv[0]; o.p[0][1] = (f16)hv[1];
            o.p[1][0] = (f16)hv[2]; o.p[1][1] = (f16)hv[3];
            *(H4*)(h + (size_t)r * HDIM + 4 * cg) = o;
            if (cg == 0) invn[r] = 1.0f / fmaxf(sqrtf(ss), 1e-12f);
        }
    }
}

// One wave per node; 4 lanes per edge, 16 edges per chunk (fp16 rows = 64B).
// eloc = lane>>2 (edge slot), c8 = lane&3 (8 h-elements each).
// Fixed-shift softmax e = exp(alpha - 1) (|alpha| <= 1 for cosine), per-slot
// denominators merged at wave end. Pipeline: 4 named row buffers (no
// rotation copies -> up to 4 row+inv gathers in flight per wave), col
// indices loaded directly per-quad (1 line/chunk, no ds_bpermute) and
// prefetched one full group ahead.
__launch_bounds__(256) __global__
void k_agnn(const f16* __restrict__ h_in, const float* __restrict__ inv_in,
            f16* __restrict__ h_out, float* __restrict__ inv_out,
            const int* __restrict__ rp, const int* __restrict__ col, int N) {
    int wave = threadIdx.x >> 6;
    int lane = threadIdx.x & 63;
    int i = blockIdx.x * 4 + wave;
    if (i >= N) return;
    int beg = rp[i];
    int deg = rp[i + 1] - beg;
    int eloc = lane >> 2;  // 0..15 edge slot
    int c8 = lane & 3;     // element group (8 halfs)
    float inv_i = inv_in[i];
    H8 hi = *(const H8*)(h_in + (size_t)i * HDIM + 8 * c8);
    float s_run = 0.0f;
    float acc[8] = {0.f, 0.f, 0.f, 0.f, 0.f, 0.f, 0.f, 0.f};
    int nchunk = (deg + 15) >> 4;

#define CLOADK(k) ((16 * (k) + eloc) < deg ? col[beg + 16 * (k) + eloc] : 0)
#define RLOAD(Rv, iv, s) do { \
        Rv = *(const H8*)(h_in + (size_t)(s) * HDIM + 8 * c8); \
        iv = inv_in[(s)]; \
    } while (0)
#define PROC(Rv, iv, vf) do { \
        float dot_ = 0.0f; \
        _Pragma("unroll") \
        for (int j_ = 0; j_ < 4; ++j_) dot_ = FDOT2(Rv.p[j_], hi.p[j_], dot_); \
        dot_ = quad_sum(dot_); \
        float e_ = (vf) ? __expf(fmaf(dot_, inv_i * (iv), -1.0f)) : 0.0f; \
        s_run += e_; \
        _Pragma("unroll") \
        for (int j_ = 0; j_ < 4; ++j_) { \
            acc[2 * j_ + 0] = fmaf(e_, (float)Rv.p[j_][0], acc[2 * j_ + 0]); \
            acc[2 * j_ + 1] = fmaf(e_, (float)Rv.p[j_][1], acc[2 * j_ + 1]); \
        } \
    } while (0)

    // ---- prologue: cols 0..3, then rows+invs 0..3, then cols 4..7
    int c0 = CLOADK(0), c1 = CLOADK(1), c2 = CLOADK(2), c3 = CLOADK(3);
    bool v0 = (eloc) < deg;
    bool v1 = (16 + eloc) < deg;
    bool v2 = (32 + eloc) < deg;
    bool v3 = (48 + eloc) < deg;
    H8 R0, R1, R2, R3;
    float i0, i1, i2, i3;
    RLOAD(R0, i0, c0);
    RLOAD(R1, i1, c1);
    RLOAD(R2, i2, c2);
    RLOAD(R3, i3, c3);
    int n0 = 0, n1 = 0, n2 = 0, n3 = 0;
    if (nchunk > 4) { n0 = CLOADK(4); n1 = CLOADK(5); n2 = CLOADK(6); n3 = CLOADK(7); }

    int g = 0;
    if (nchunk > 4) {
        while (true) {
            PROC(R0, i0, v0); v0 = (16 * (g + 4) + eloc) < deg; RLOAD(R0, i0, n0);
            PROC(R1, i1, v1); v1 = (16 * (g + 5) + eloc) < deg; RLOAD(R1, i1, n1);
            PROC(R2, i2, v2); v2 = (16 * (g + 6) + eloc) < deg; RLOAD(R2, i2, n2);
            PROC(R3, i3, v3); v3 = (16 * (g + 7) + eloc) < deg; RLOAD(R3, i3, n3);
            g += 4;
            if (g + 4 >= nchunk) break;
            n0 = CLOADK(g + 4); n1 = CLOADK(g + 5);
            n2 = CLOADK(g + 6); n3 = CLOADK(g + 7);
        }
    }
    // ---- tail: 1..4 chunks remain in R0..R3
    int rem = nchunk - g;
    PROC(R0, i0, v0);
    if (rem > 1) PROC(R1, i1, v1);
    if (rem > 2) PROC(R2, i2, v2);
    if (rem > 3) PROC(R3, i3, v3);

#undef CLOADK
#undef RLOAD
#undef PROC

    // merge partials across the 16 edge slots (fixed c8)
    float s_tot = s_run;
#pragma unroll
    for (int mask = 4; mask <= 32; mask <<= 1) s_tot += __shfl_xor(s_tot, mask);
#pragma unroll
    for (int mask = 4; mask <= 32; mask <<= 1) {
#pragma unroll
        for (int j = 0; j < 8; ++j) acc[j] += __shfl_xor(acc[j], mask);
    }
    float invs = 1.0f / s_tot;  // s_tot >= exp(-2) > 0 (self loop)
    float ss = 0.0f;
#pragma unroll
    for (int j = 0; j < 8; ++j) {
        acc[j] *= invs;
        ss = fmaf(acc[j], acc[j], ss);
    }
    ss = quad_sum(ss);  // sum over the 4 c8 groups
    if (lane < 4) {  // eloc==0: c8 = lane
        H8 o;
#pragma unroll
        for (int j = 0; j < 4; ++j) {
            o.p[j][0] = (f16)acc[2 * j + 0];
            o.p[j][1] = (f16)acc[2 * j + 1];
        }
        *(H8*)(h_out + (size_t)i * HDIM + 8 * lane) = o;
        if (lane == 0) inv_out[i] = 1.0f / fmaxf(sqrtf(ss), 1e-12f);
    }
}

__launch_bounds__(256) __global__
void k_gemm2(const f16* __restrict__ h, const float* __restrict__ W2,
             const float* __restrict__ b2, float* __restrict__ out, int N) {
    int wave = threadIdx.x >> 6;
    int lane = threadIdx.x & 63;
    int i = blockIdx.x * 4 + wave;
    if (i >= N) return;
    bool act = lane < 40;
    float acc = act ? b2[lane] : 0.0f;
    const f16* hr = h + (size_t)i * HDIM;
#pragma unroll
    for (int k = 0; k < HDIM; ++k) {
        float hk = (float)hr[k];
        float w = act ? W2[k * 40 + lane] : 0.0f;
        acc = fmaf(hk, w, acc);
    }
    float logit = act ? acc : -INFINITY;
    float m = logit;
#pragma unroll
    for (int mask = 32; mask >= 1; mask >>= 1) m = fmaxf(m, __shfl_xor(m, mask));
    float e = act ? __expf(logit - m) : 0.0f;
    float s = e;
#pragma unroll
    for (int mask = 32; mask >= 1; mask >>= 1) s += __shfl_xor(s, mask);
    float res = logit - m - __logf(s);
    if (act) out[(size_t)i * 40 + lane] = res;
}

extern "C" void kernel_launch(void* const* d_in, const int* in_sizes, int n_in,
                              void* d_out, int out_size, void* d_ws, size_t ws_size,
                              hipStream_t stream) {
    const float* x  = (const float*)d_in[0];
    const int*   e  = (const int*)d_in[1];
    const float* W1 = (const float*)d_in[2];
    const float* b1 = (const float*)d_in[3];
    const float* W2 = (const float*)d_in[4];
    const float* b2 = (const float*)d_in[5];
    float* out = (float*)d_out;

    const long long E = (long long)in_sizes[1] / 2;
    const int N = in_sizes[0] / 512;  // F_in = 512
    const long long M = E + N;
    const int nblk = (int)((M + CHUNK - 1) / CHUNK);

    char* w = (char*)d_ws;
    auto alloc = [&](size_t bytes) -> void* {
        void* p = (void*)w;
        w += (bytes + 255) & ~(size_t)255;
        return p;
    };
    int*  flag      = (int*)alloc(4);
    int*  gc        = (int*)alloc(NBMAX * 4);
    int*  bbase     = (int*)alloc((NBMAX + 1) * 4);
    int*  blockOffs = (int*)alloc((size_t)nblk * NBMAX * 4);
    int2* pair      = (int2*)alloc((size_t)M * 8);
    int*  rp        = (int*)alloc(((size_t)N + 1) * 4);
    int*  col       = (int*)alloc((size_t)M * 4);
    f16*  hA   = (f16*)alloc((size_t)N * HDIM * 2);
    f16*  hB   = (f16*)alloc((size_t)N * HDIM * 2);
    float* invA = (float*)alloc((size_t)N * 4);
    float* invB = (float*)alloc((size_t)N * 4);
    if ((size_t)(w - (char*)d_ws) > ws_size) return;

    k_flag<<<1, 64, 0, stream>>>(e, flag);
    k_zero<<<(NBMAX + 255) / 256, 256, 0, stream>>>(gc, NBMAX);
    k_hist<<<nblk, 256, 0, stream>>>(e, flag, gc, blockOffs, E, M);
    k_bscan<<<1, 256, 0, stream>>>(gc, bbase, rp, N);
    k_part<<<nblk, 256, 0, stream>>>(e, flag, bbase, blockOffs, pair, E, M);
    k_fine<<<NBMAX, 256, 0, stream>>>(pair, bbase, rp, col, N);

    k_gemm1<<<(N + 127) / 128, 256, 0, stream>>>(x, W1, b1, hA, invA, N);

    f16 *hin = hA, *hout = hB;
    float *iin = invA, *iout = invB;
    for (int l = 0; l < 32; ++l) {
        k_agnn<<<(N + 3) / 4, 256, 0, stream>>>(hin, iin, hout, iout, rp, col, N);
        f16* t = hin; hin = hout; hout = t;
        float* ti = iin; iin = iout; iout = ti;
    }
    k_gemm2<<<(N + 3) / 4, 256, 0, stream>>>(hin, W2, b2, out, N);
}

// Round 5
// 2097.003 us; speedup vs baseline: 1.0757x; 1.0757x over previous
//
#include <hip/hip_runtime.h>
#include <math.h>

// ---------------------------------------------------------------------------
// AGNN stack: h=relu(x@W1+b1); 32x AGNNConv(beta=1); log_softmax(h@W2+b2)
// N=100000, F=512, H=32, C=40, E=3200000 (+N self loops)
// R9: (a) k_agnn reverted to the measured-best R6 schedule (58.9 us/layer);
//     three different schedules measured within 5% -> agnn is bound by the
//     random-gather machine, not intra-wave scheduling. Smallest-register
//     variant wins.
//     (b) k_gemm1 rewritten on MFMA 16x16x32_f16: wave per 16-row tile,
//     x cast fp32->fp16 in-register (full-line streaming loads), W1
//     pre-transposed+converted to fp16 (32KB, L2-hot, read directly),
//     fp32 accum, fused bias+relu+fp16 store+invn. A/B fragments use the
//     same (lane>>4,reg)->k placement so any HW k-permutation cancels.
// ---------------------------------------------------------------------------

#define HDIM 32
#define NBMAX 1024   // bucket table size (needs N <= 128*1024)
#define BSH 7        // 128 dsts per bucket
#define CHUNK 32768  // edges per partition block

typedef _Float16 f16;
typedef _Float16 v2h __attribute__((ext_vector_type(2)));
typedef _Float16 f16x8 __attribute__((ext_vector_type(8)));
typedef float f32x4 __attribute__((ext_vector_type(4)));

struct __attribute__((aligned(16))) H8 { v2h p[4]; };  // one fp16 half-row (8 elems)
struct __attribute__((aligned(8)))  H4 { v2h p[2]; };  // 4 fp16 elems

#if defined(__has_builtin)
#if __has_builtin(__builtin_amdgcn_fdot2)
#define FDOT2(a, b, c) __builtin_amdgcn_fdot2((a), (b), (c), false)
#endif
#if __has_builtin(__builtin_amdgcn_update_dpp)
#define HAS_DPP 1
#endif
#endif
#ifndef FDOT2
#define FDOT2(a, b, c) fmaf((float)(a)[1], (float)(b)[1], fmaf((float)(a)[0], (float)(b)[0], (c)))
#endif

// sum over each aligned 4-lane quad (lanes l^1, l^2) — DPP, no LDS pipe
static __device__ __forceinline__ float quad_sum(float x) {
#ifdef HAS_DPP
    x += __int_as_float(__builtin_amdgcn_update_dpp(
        0, __float_as_int(x), 0xB1 /*quad_perm [1,0,3,2]*/, 0xF, 0xF, true));
    x += __int_as_float(__builtin_amdgcn_update_dpp(
        0, __float_as_int(x), 0x4E /*quad_perm [2,3,0,1]*/, 0xF, 0xF, true));
#else
    x += __shfl_xor(x, 1);
    x += __shfl_xor(x, 2);
#endif
    return x;
}

static __device__ __forceinline__ int eread(const int* __restrict__ e, int i64, long long idx) {
    return i64 ? e[2 * idx] : e[idx];
}

__global__ void k_flag(const int* __restrict__ e, int* __restrict__ flag) {
    if (blockIdx.x == 0 && threadIdx.x == 0) {
        int z = 0;
        for (int k = 0; k < 64; ++k) z |= e[2 * k + 1];
        *flag = (z == 0) ? 1 : 0;
    }
}

__global__ void k_zero(int* __restrict__ p, int n) {
    int i = blockIdx.x * blockDim.x + threadIdx.x;
    if (i < n) p[i] = 0;
}

// Pass 1: per-block LDS histogram over dst buckets + global reserve.
__launch_bounds__(256) __global__
void k_hist(const int* __restrict__ e, const int* __restrict__ flag,
            int* __restrict__ gc, int* __restrict__ blockOffs,
            long long E, long long M) {
    __shared__ int bh[NBMAX];
    for (int t = threadIdx.x; t < NBMAX; t += 256) bh[t] = 0;
    __syncthreads();
    int i64 = *flag;
    long long base = (long long)blockIdx.x * CHUNK;
    long long end = base + CHUNK < M ? base + CHUNK : M;
    for (long long m = base + threadIdx.x; m < end; m += 256) {
        int d = (m < E) ? eread(e, i64, E + m) : (int)(m - E);
        atomicAdd(&bh[d >> BSH], 1);
    }
    __syncthreads();
    for (int t = threadIdx.x; t < NBMAX; t += 256) {
        int c = bh[t];
        int off = 0;
        if (c) off = atomicAdd(&gc[t], c);
        blockOffs[(size_t)blockIdx.x * NBMAX + t] = off;
    }
}

__launch_bounds__(256) __global__
void k_bscan(const int* __restrict__ gc, int* __restrict__ bbase,
             int* __restrict__ rp, int N) {
    __shared__ int lds[256];
    int t = threadIdx.x;
    int v[4];
#pragma unroll
    for (int d = 0; d < 4; ++d) v[d] = gc[t * 4 + d];
    int tsum = v[0] + v[1] + v[2] + v[3];
    lds[t] = tsum;
    __syncthreads();
    int acc = tsum;
    for (int sh = 1; sh < 256; sh <<= 1) {
        int x = (t >= sh) ? lds[t - sh] : 0;
        __syncthreads();
        acc += x;
        lds[t] = acc;
        __syncthreads();
    }
    if (t == 255) { rp[N] = acc; bbase[NBMAX] = acc; }
    int run = acc - tsum;
#pragma unroll
    for (int d = 0; d < 4; ++d) { bbase[t * 4 + d] = run; run += v[d]; }
}

// Pass 2: partition edges into bucket regions.
__launch_bounds__(256) __global__
void k_part(const int* __restrict__ e, const int* __restrict__ flag,
            const int* __restrict__ bbase, const int* __restrict__ blockOffs,
            int2* __restrict__ pair, long long E, long long M) {
    __shared__ int cur[NBMAX];
    for (int t = threadIdx.x; t < NBMAX; t += 256)
        cur[t] = bbase[t] + blockOffs[(size_t)blockIdx.x * NBMAX + t];
    __syncthreads();
    int i64 = *flag;
    long long base = (long long)blockIdx.x * CHUNK;
    long long end = base + CHUNK < M ? base + CHUNK : M;
    for (long long m = base + threadIdx.x; m < end; m += 256) {
        int s, d;
        if (m < E) { s = eread(e, i64, m); d = eread(e, i64, E + m); }
        else { s = d = (int)(m - E); }
        int pos = atomicAdd(&cur[d >> BSH], 1);
        pair[pos] = make_int2(s, d);
    }
}

// Pass 3: one block per bucket -> fine CSR (rp + col), all LDS atomics.
__launch_bounds__(256) __global__
void k_fine(const int2* __restrict__ pair, const int* __restrict__ bbase,
            int* __restrict__ rp, int* __restrict__ col, int N) {
    __shared__ int cnt[128];
    __shared__ int sc[128];
    int b = blockIdx.x;
    int beg = bbase[b];
    int end = bbase[b + 1];
    int t = threadIdx.x;
    if (t < 128) cnt[t] = 0;
    __syncthreads();
    for (int k = beg + t; k < end; k += 256)
        atomicAdd(&cnt[pair[k].y & 127], 1);
    __syncthreads();
    if (t < 128) sc[t] = cnt[t];
    __syncthreads();
    for (int sh = 1; sh < 128; sh <<= 1) {
        int x = 0;
        if (t < 128 && t >= sh) x = sc[t - sh];
        __syncthreads();
        if (t < 128) sc[t] += x;
        __syncthreads();
    }
    if (t < 128) {
        int basepos = beg + sc[t] - cnt[t];
        int d = (b << BSH) + t;
        if (d < N) rp[d] = basepos;
        cnt[t] = basepos;
    }
    __syncthreads();
    for (int k = beg + t; k < end; k += 256) {
        int2 p = pair[k];
        int pos = atomicAdd(&cnt[p.y & 127], 1);
        col[pos] = p.x;
    }
}

// W1 (512x32 fp32, row-major) -> W1hT (32x512 fp16, transposed).
__global__ void k_w1cvt(const float* __restrict__ W1, f16* __restrict__ W1hT) {
    int t = blockIdx.x * 256 + threadIdx.x;
    if (t < 512 * 32) {
        int k = t >> 5, j = t & 31;
        W1hT[(size_t)j * 512 + k] = (f16)W1[t];
    }
}

// h = relu(x @ W1 + b1) + fused inv_norm via MFMA 16x16x32_f16.
// One wave per 16-row tile. A: x rows cast fp32->fp16 (lane: row=l&15,
// k = ks*32 + 8*(l>>4) + t). B: W1hT[j][k] with the SAME k placement ->
// exact under any HW k-slot permutation. C/D: row=4*(l>>4)+r, col=l&15
// (verified m89 mapping). fp32 accum; bias+relu+fp16 store+invn fused.
__launch_bounds__(256) __global__
void k_gemm1(const float* __restrict__ x, const f16* __restrict__ W1hT,
             const float* __restrict__ b1, f16* __restrict__ h,
             float* __restrict__ invn, int N) {
    int wid = (blockIdx.x * 256 + threadIdx.x) >> 6;
    int lane = threadIdx.x & 63;
    int ntile = (N + 15) >> 4;
    if (wid >= ntile) return;
    int j16 = lane & 15;   // A row offset / B col
    int kb = lane >> 4;    // k-block 0..3
    int rload = wid * 16 + j16;
    if (rload > N - 1) rload = N - 1;  // clamp (harmless duplicate loads)
    const float* xr = x + (size_t)rload * 512 + kb * 8;
    const f16* w0 = W1hT + (size_t)j16 * 512 + kb * 8;
    const f16* w1 = W1hT + (size_t)(j16 + 16) * 512 + kb * 8;
    f32x4 acc0 = {0.f, 0.f, 0.f, 0.f};
    f32x4 acc1 = {0.f, 0.f, 0.f, 0.f};
#pragma unroll 4
    for (int ks = 0; ks < 16; ++ks) {
        float4 xa = *(const float4*)(xr + ks * 32);
        float4 xb = *(const float4*)(xr + ks * 32 + 4);
        f16x8 a;
        a[0] = (f16)xa.x; a[1] = (f16)xa.y; a[2] = (f16)xa.z; a[3] = (f16)xa.w;
        a[4] = (f16)xb.x; a[5] = (f16)xb.y; a[6] = (f16)xb.z; a[7] = (f16)xb.w;
        f16x8 b0 = *(const f16x8*)(w0 + ks * 32);
        f16x8 b1v = *(const f16x8*)(w1 + ks * 32);
        acc0 = __builtin_amdgcn_mfma_f32_16x16x32_f16(a, b0, acc0, 0, 0, 0);
        acc1 = __builtin_amdgcn_mfma_f32_16x16x32_f16(a, b1v, acc1, 0, 0, 0);
    }
    float bias0 = b1[j16];
    float bias1 = b1[j16 + 16];
#pragma unroll
    for (int r = 0; r < 4; ++r) {
        float v0 = fmaxf(acc0[r] + bias0, 0.0f);
        float v1 = fmaxf(acc1[r] + bias1, 0.0f);
        float ss = fmaf(v0, v0, v1 * v1);
        ss += __shfl_xor(ss, 1);
        ss += __shfl_xor(ss, 2);
        ss += __shfl_xor(ss, 4);
        ss += __shfl_xor(ss, 8);  // sum over the 16 col lanes
        int row = wid * 16 + 4 * kb + r;
        if (row < N) {
            h[(size_t)row * HDIM + j16] = (f16)v0;
            h[(size_t)row * HDIM + j16 + 16] = (f16)v1;
            if (j16 == 0) invn[row] = 1.0f / fmaxf(sqrtf(ss), 1e-12f);
        }
    }
}

// One wave per node; 4 lanes per edge, 16 edges per chunk (fp16 rows = 64B).
// eloc = lane>>2 (edge slot), c8 = lane&3 (8 h-elements each).
// Cosine attention is bounded: |alpha| <= 1 (+fp16 eps), so softmax uses the
// FIXED shift e = exp(alpha - 1) — exact by shift invariance. Per-slot
// denominators merged at wave end. Depth-2 pipeline (measured-best R6).
__launch_bounds__(256) __global__
void k_agnn(const f16* __restrict__ h_in, const float* __restrict__ inv_in,
            f16* __restrict__ h_out, float* __restrict__ inv_out,
            const int* __restrict__ rp, const int* __restrict__ col, int N) {
    int wave = threadIdx.x >> 6;
    int lane = threadIdx.x & 63;
    int i = blockIdx.x * 4 + wave;
    if (i >= N) return;
    int beg = rp[i];
    int deg = rp[i + 1] - beg;
    int eloc = lane >> 2;  // 0..15 edge slot
    int c8 = lane & 3;     // element group (8 halfs)
    float inv_i = inv_in[i];
    H8 hi = *(const H8*)(h_in + (size_t)i * HDIM + 8 * c8);
    float s_run = 0.0f;  // per-slot softmax denominator partial
    float acc[8] = {0.f, 0.f, 0.f, 0.f, 0.f, 0.f, 0.f, 0.f};
    int nchunk = (deg + 15) >> 4;
    // col batch covers chunks 0..3
    int cv = (lane < deg) ? col[beg + lane] : 0;
    // depth-2 software pipeline: A = chunk ck, B = chunk ck+1
    H8 rA, rB;
    float iA, iB = 0.0f;
    bool vA, vB = false;
    {
        vA = eloc < deg;  // deg >= 1 always (self loop)
        int s = __shfl(cv, eloc);
        s = vA ? s : 0;
        rA = *(const H8*)(h_in + (size_t)s * HDIM + 8 * c8);
        iA = inv_in[s];
    }
    if (nchunk > 1) {
        int idx = 16 + eloc;
        vB = idx < deg;
        int s = __shfl(cv, 16 | eloc);
        s = vB ? s : 0;
        rB = *(const H8*)(h_in + (size_t)s * HDIM + 8 * c8);
        iB = inv_in[s];
    } else {
        rB = hi;  // keep registers initialized; never consumed
    }
    for (int ck = 0; ck < nchunk; ++ck) {
        H8 rc = rA;
        float ic = iA;
        bool vc = vA;
        rA = rB; iA = iB; vA = vB;
        int nc = ck + 2;
        if (nc < nchunk) {  // wave-uniform branch: issue chunk ck+2
            if ((nc & 3) == 0) {
                int idx64 = nc * 16 + lane;
                cv = (idx64 < deg) ? col[beg + idx64] : 0;
            }
            int idx = nc * 16 + eloc;
            vB = idx < deg;
            int s = __shfl(cv, ((nc & 3) << 4) | eloc);
            s = vB ? s : 0;
            rB = *(const H8*)(h_in + (size_t)s * HDIM + 8 * c8);
            iB = inv_in[s];
        }
        // 32-elem dot within the 4-lane quad (fp32 accum, DPP reduce)
        float dot = 0.0f;
#pragma unroll
        for (int j = 0; j < 4; ++j) dot = FDOT2(rc.p[j], hi.p[j], dot);
        dot = quad_sum(dot);
        // alpha = cos in [-1,1]; fixed-shift softmax term
        float e = vc ? __expf(fmaf(dot, inv_i * ic, -1.0f)) : 0.0f;
        s_run += e;
#pragma unroll
        for (int j = 0; j < 4; ++j) {
            acc[2 * j + 0] = fmaf(e, (float)rc.p[j][0], acc[2 * j + 0]);
            acc[2 * j + 1] = fmaf(e, (float)rc.p[j][1], acc[2 * j + 1]);
        }
    }
    // merge partials across the 16 edge slots (fixed c8)
    float s_tot = s_run;
#pragma unroll
    for (int mask = 4; mask <= 32; mask <<= 1) s_tot += __shfl_xor(s_tot, mask);
#pragma unroll
    for (int mask = 4; mask <= 32; mask <<= 1) {
#pragma unroll
        for (int j = 0; j < 8; ++j) acc[j] += __shfl_xor(acc[j], mask);
    }
    float invs = 1.0f / s_tot;  // s_tot >= exp(-2) > 0 (self loop)
    float ss = 0.0f;
#pragma unroll
    for (int j = 0; j < 8; ++j) {
        acc[j] *= invs;
        ss = fmaf(acc[j], acc[j], ss);
    }
    ss = quad_sum(ss);  // sum over the 4 c8 groups
    if (lane < 4) {  // eloc==0: c8 = lane
        H8 o;
#pragma unroll
        for (int j = 0; j < 4; ++j) {
            o.p[j][0] = (f16)acc[2 * j + 0];
            o.p[j][1] = (f16)acc[2 * j + 1];
        }
        *(H8*)(h_out + (size_t)i * HDIM + 8 * lane) = o;
        if (lane == 0) inv_out[i] = 1.0f / fmaxf(sqrtf(ss), 1e-12f);
    }
}

__launch_bounds__(256) __global__
void k_gemm2(const f16* __restrict__ h, const float* __restrict__ W2,
             const float* __restrict__ b2, float* __restrict__ out, int N) {
    int wave = threadIdx.x >> 6;
    int lane = threadIdx.x & 63;
    int i = blockIdx.x * 4 + wave;
    if (i >= N) return;
    bool act = lane < 40;
    float acc = act ? b2[lane] : 0.0f;
    const f16* hr = h + (size_t)i * HDIM;
#pragma unroll
    for (int k = 0; k < HDIM; ++k) {
        float hk = (float)hr[k];
        float w = act ? W2[k * 40 + lane] : 0.0f;
        acc = fmaf(hk, w, acc);
    }
    float logit = act ? acc : -INFINITY;
    float m = logit;
#pragma unroll
    for (int mask = 32; mask >= 1; mask >>= 1) m = fmaxf(m, __shfl_xor(m, mask));
    float e = act ? __expf(logit - m) : 0.0f;
    float s = e;
#pragma unroll
    for (int mask = 32; mask >= 1; mask >>= 1) s += __shfl_xor(s, mask);
    float res = logit - m - __logf(s);
    if (act) out[(size_t)i * 40 + lane] = res;
}

extern "C" void kernel_launch(void* const* d_in, const int* in_sizes, int n_in,
                              void* d_out, int out_size, void* d_ws, size_t ws_size,
                              hipStream_t stream) {
    const float* x  = (const float*)d_in[0];
    const int*   e  = (const int*)d_in[1];
    const float* W1 = (const float*)d_in[2];
    const float* b1 = (const float*)d_in[3];
    const float* W2 = (const float*)d_in[4];
    const float* b2 = (const float*)d_in[5];
    float* out = (float*)d_out;

    const long long E = (long long)in_sizes[1] / 2;
    const int N = in_sizes[0] / 512;  // F_in = 512
    const long long M = E + N;
    const int nblk = (int)((M + CHUNK - 1) / CHUNK);

    char* w = (char*)d_ws;
    auto alloc = [&](size_t bytes) -> void* {
        void* p = (void*)w;
        w += (bytes + 255) & ~(size_t)255;
        return p;
    };
    int*  flag      = (int*)alloc(4);
    int*  gc        = (int*)alloc(NBMAX * 4);
    int*  bbase     = (int*)alloc((NBMAX + 1) * 4);
    int*  blockOffs = (int*)alloc((size_t)nblk * NBMAX * 4);
    int2* pair      = (int2*)alloc((size_t)M * 8);
    int*  rp        = (int*)alloc(((size_t)N + 1) * 4);
    int*  col       = (int*)alloc((size_t)M * 4);
    f16*  hA   = (f16*)alloc((size_t)N * HDIM * 2);
    f16*  hB   = (f16*)alloc((size_t)N * HDIM * 2);
    float* invA = (float*)alloc((size_t)N * 4);
    float* invB = (float*)alloc((size_t)N * 4);
    f16*  W1hT = (f16*)alloc((size_t)512 * 32 * 2);
    if ((size_t)(w - (char*)d_ws) > ws_size) return;

    k_flag<<<1, 64, 0, stream>>>(e, flag);
    k_zero<<<(NBMAX + 255) / 256, 256, 0, stream>>>(gc, NBMAX);
    k_hist<<<nblk, 256, 0, stream>>>(e, flag, gc, blockOffs, E, M);
    k_bscan<<<1, 256, 0, stream>>>(gc, bbase, rp, N);
    k_part<<<nblk, 256, 0, stream>>>(e, flag, bbase, blockOffs, pair, E, M);
    k_fine<<<NBMAX, 256, 0, stream>>>(pair, bbase, rp, col, N);

    k_w1cvt<<<64, 256, 0, stream>>>(W1, W1hT);
    int ntile = (N + 15) >> 4;
    k_gemm1<<<(ntile + 3) / 4, 256, 0, stream>>>(x, W1hT, b1, hA, invA, N);

    f16 *hin = hA, *hout = hB;
    float *iin = invA, *iout = invB;
    for (int l = 0; l < 32; ++l) {
        k_agnn<<<(N + 3) / 4, 256, 0, stream>>>(hin, iin, hout, iout, rp, col, N);
        f16* t = hin; hin = hout; hout = t;
        float* ti = iin; iin = iout; iout = ti;
    }
    k_gemm2<<<(N + 3) / 4, 256, 0, stream>>>(hin, W2, b2, out, N);
}